// Round 6
// baseline (215.459 us; speedup 1.0000x reference)
//
#include <hip/hip_runtime.h>

// B=4, T=4096, C=512, H=64 causal attention head, scale=C^-0.5, fp32 I/O.
// R17 = R16 + merge fused into attn via last-arriver atomic counter
// (device-scope fences for cross-XCD visibility); merge_kernel removed.
// wt_kernel zeroes the 128 per-(b,qmt) counters each launch.

typedef __attribute__((ext_vector_type(8))) __bf16 bf16x8;
typedef __attribute__((ext_vector_type(8))) unsigned short u16x8;
typedef __attribute__((ext_vector_type(4))) float f32x4;

#define B_ 4
#define T_ 4096
#define C_ 512
#define H_ 64
#define BT (B_ * T_)

#define QSCALE (0.04419417382415922f * 1.4426950408889634f)  // C^-0.5 * log2(e)

__device__ __forceinline__ unsigned short f2bf(float f) {
    unsigned int u = __builtin_bit_cast(unsigned int, f);
    u += 0x7fffu + ((u >> 16) & 1u);
    return (unsigned short)(u >> 16);
}

__device__ __forceinline__ unsigned int pkbf(float hi, float lo) {
    return __builtin_amdgcn_perm(__builtin_bit_cast(unsigned int, hi),
                                 __builtin_bit_cast(unsigned int, lo), 0x07060302u);
}

__device__ __forceinline__ float bf2f_lo(unsigned int u) {
    return __builtin_bit_cast(float, u << 16);
}
__device__ __forceinline__ float bf2f_hi(unsigned int u) {
    return __builtin_bit_cast(float, u & 0xffff0000u);
}

__device__ __forceinline__ f32x4 mfma16(bf16x8 a, bf16x8 b, f32x4 c) {
    return __builtin_amdgcn_mfma_f32_16x16x32_bf16(a, b, c, 0, 0, 0);
}

// async global->LDS, 16B per lane; lds dest must be the wave-uniform base.
__device__ __forceinline__ void gload_lds16(const void* g, void* lds_uniform) {
    __builtin_amdgcn_global_load_lds(
        (const __attribute__((address_space(1))) unsigned int*)g,
        (__attribute__((address_space(3))) unsigned int*)lds_uniform, 16, 0, 0);
}

// ---------------------------------------------------------------------------
// Kernel 0: Wt packed in MFMA B-fragment order + zero merge counters.
// ---------------------------------------------------------------------------
__global__ __launch_bounds__(256) void wt_kernel(const float* __restrict__ Wk,
                                                 const float* __restrict__ Wq,
                                                 const float* __restrict__ Wv,
                                                 unsigned short* __restrict__ Wtp,
                                                 int* __restrict__ cnt) {
    int gid = blockIdx.x * 256 + threadIdx.x;  // 3*64*512
    if (gid < 128) cnt[gid] = 0;               // 4 b x 32 qmt counters
    int fidx = gid >> 9;
    int li = gid & 511;
    int lane = li >> 3, j = li & 7;
    int m3 = fidx / 64;
    int rem = fidx & 63;
    int nt = rem >> 4, kc = rem & 15;
    int h = nt * 16 + (lane & 15);
    int c = kc * 32 + (lane >> 4) * 8 + j;
    const float* W = (m3 == 0) ? Wk : ((m3 == 1) ? Wq : Wv);
    Wtp[gid] = f2bf(W[c * H_ + h]);
}

// ---------------------------------------------------------------------------
// Kernel 1: projections. 32 rows/block, 256 thr = 2 strips x 2 kc-halves,
// register prefetch of x TWO kc ahead (HBM latency) + W one kc ahead (L2).
// ---------------------------------------------------------------------------
__global__ __launch_bounds__(256, 3) void proj_kernel(const float* __restrict__ x,
                                                      const unsigned short* __restrict__ Wtp,
                                                      unsigned short* __restrict__ Kf,
                                                      unsigned short* __restrict__ Qf,
                                                      unsigned short* __restrict__ Vf) {
    __shared__ __align__(16) char smem[2 * 64 * 52 * 4];   // 26624 B
    float* Mg = (float*)smem;                               // [2][64][52] f32
    unsigned short* Ks_l = (unsigned short*)smem;           // [32][68]
    unsigned short* Qs_l = Ks_l + 32 * 68;
    unsigned short* Vt_l = Qs_l + 32 * 68;                  // [64 h][34]

    const int tid = threadIdx.x;
    const int t0 = blockIdx.x * 32;
    const int wave = tid >> 6;
    const int ws = wave & 1;       // strip
    const int wh = wave >> 1;      // kc half
    const int lane = tid & 63;
    const int lane15 = lane & 15;
    const int quad = lane >> 4;

    f32x4 acc[12];
#pragma unroll
    for (int i = 0; i < 12; ++i) acc[i] = (f32x4){0.f, 0.f, 0.f, 0.f};

    const float* xrow = x + (long)(t0 + ws * 16 + lane15) * C_;
    const unsigned short* wbase = Wtp + lane * 8;

    bf16x8 wf[12];
    float4 xa0[2], xa1[2];
    {
        const int kc0 = wh * 8;
        xa0[0] = *(const float4*)(xrow + kc0 * 32 + quad * 8);
        xa1[0] = *(const float4*)(xrow + kc0 * 32 + quad * 8 + 4);
        xa0[1] = *(const float4*)(xrow + (kc0 + 1) * 32 + quad * 8);
        xa1[1] = *(const float4*)(xrow + (kc0 + 1) * 32 + quad * 8 + 4);
#pragma unroll
        for (int i = 0; i < 12; ++i)
            wf[i] = *(const bf16x8*)(wbase + ((i * 16 + kc0) << 9));
    }

#pragma unroll
    for (int kk = 0; kk < 8; ++kk) {
        const int kc = wh * 8 + kk;
        const int cur = kk & 1;
        u16x8 t;
        t[0] = f2bf(xa0[cur].x); t[1] = f2bf(xa0[cur].y);
        t[2] = f2bf(xa0[cur].z); t[3] = f2bf(xa0[cur].w);
        t[4] = f2bf(xa1[cur].x); t[5] = f2bf(xa1[cur].y);
        t[6] = f2bf(xa1[cur].z); t[7] = f2bf(xa1[cur].w);
        bf16x8 a = __builtin_bit_cast(bf16x8, t);
        if (kk < 6) {
            xa0[cur] = *(const float4*)(xrow + (kc + 2) * 32 + quad * 8);
            xa1[cur] = *(const float4*)(xrow + (kc + 2) * 32 + quad * 8 + 4);
        }
        __builtin_amdgcn_s_setprio(1);
#pragma unroll
        for (int i = 0; i < 12; ++i) {
            acc[i] = mfma16(a, wf[i], acc[i]);
            if (kk < 7)
                wf[i] = *(const bf16x8*)(wbase + ((i * 16 + kc + 1) << 9));
        }
        __builtin_amdgcn_s_setprio(0);
    }

    // kc merge through LDS
    if (wh == 1) {
        float* mg = Mg + (ws * 64 + lane) * 52;
#pragma unroll
        for (int i = 0; i < 12; ++i) *(f32x4*)(mg + i * 4) = acc[i];
    }
    __syncthreads();
    if (wh == 0) {
        const float* mg = Mg + (ws * 64 + lane) * 52;
#pragma unroll
        for (int i = 0; i < 12; ++i) acc[i] += *(const f32x4*)(mg + i * 4);
    }
    __syncthreads();  // Mg dead

    if (wh == 0) {
#pragma unroll
        for (int nt = 0; nt < 4; ++nt) {
            int col = nt * 16 + lane15;
#pragma unroll
            for (int r = 0; r < 4; ++r) {
                int row_l = ws * 16 + quad * 4 + r;
                Ks_l[row_l * 68 + col] = f2bf(acc[0 * 4 + nt][r]);
                Qs_l[row_l * 68 + col] = f2bf(acc[1 * 4 + nt][r] * QSCALE);
                Vt_l[col * 34 + row_l] = f2bf(acc[2 * 4 + nt][r]);
            }
        }
    }
    __syncthreads();

    const int b = t0 >> 12;
    const int tloc = t0 & 4095;
    const int st = wave >> 1, kk = wave & 1;
    const long gs = (long)(b * 256 + (tloc >> 4) + st);
    bf16x8 kv = *(const bf16x8*)&Ks_l[(st * 16 + lane15) * 68 + kk * 32 + quad * 8];
    *(bf16x8*)&Kf[(gs * 2 + kk) * 512 + lane * 8] = kv;
    bf16x8 qv = *(const bf16x8*)&Qs_l[(st * 16 + lane15) * 68 + kk * 32 + quad * 8];
    *(bf16x8*)&Qf[(gs * 2 + kk) * 512 + lane * 8] = qv;
    const int hf = wave;
    const int vkk = (tloc >> 5) & 1;
    bf16x8 vv = *(const bf16x8*)&Vt_l[(hf * 16 + lane15) * 34 + quad * 8];
    const long sb = (long)(b * 64 + (tloc >> 6));
    *(bf16x8*)&Vf[(sb * 8 + hf * 2 + vkk) * 512 + lane * 8] = vv;
}

// ---------------------------------------------------------------------------
// Kernel 2: attention + fused last-arriver merge. Block = (b, 128-row q
// macro-tile, chunk of <=8 K tiles). 4 waves x 2 q-subtiles. K/V LDS-staged
// (global_load_lds, dbuf, counted vmcnt + raw barriers).
// ---------------------------------------------------------------------------
#define PSP 72

__global__ __launch_bounds__(256, 3) void attn_kernel(const unsigned short* __restrict__ Qf,
                                                      const unsigned short* __restrict__ Kf,
                                                      const unsigned short* __restrict__ Vf,
                                                      unsigned short* __restrict__ Opb,
                                                      float* __restrict__ lp,
                                                      int* __restrict__ cnt,
                                                      float* __restrict__ out) {
    __shared__ __align__(16) unsigned short KV[2][8192];       // 32 KB: [buf][K 8KB | V 8KB]
    __shared__ __align__(16) unsigned short Ps[8][16 * PSP];   // 18432 B: [wave*2+sub]
    __shared__ int is_last;

    const int tid = threadIdx.x;
    const int wave = tid >> 6;
    const int lane = tid & 63;
    const int lane15 = lane & 15;
    const int quad = lane >> 4;
    const int b = blockIdx.y;

    // 144 blocks/batch; group g = qmt>>2 has 4 qmt x (g+1) chunks, base
    // 2g(g+1). Longest chunks first.
    const int z = 143 - blockIdx.x;
    int g = (int)((__builtin_sqrtf(2.0f * (float)z + 1.0f) - 1.0f) * 0.5f);
    while (2 * (g + 1) * (g + 2) <= z) ++g;
    while (2 * g * (g + 1) > z) --g;
    const int idx = z - 2 * g * (g + 1);
    const int qmt = g * 4 + idx / (g + 1);
    const int chunk = idx % (g + 1);
    const int ntt = min(8, 2 * qmt + 2 - chunk * 8);
    const int t0k = chunk * 8;
    const int dt0 = 2 * qmt, dt1 = 2 * qmt + 1;
    const int qg0 = qmt * 128 + wave * 16 + lane15;

    // Q fragments for both sub-tiles
    const long gq = (long)(b * 256 + qmt * 8 + wave);
    const unsigned short* qb = Qf + gq * 1024 + lane * 8;
    const bf16x8 qf00 = *(const bf16x8*)qb;
    const bf16x8 qf01 = *(const bf16x8*)(qb + 512);
    const bf16x8 qf10 = *(const bf16x8*)(qb + 4096);
    const bf16x8 qf11 = *(const bf16x8*)(qb + 4096 + 512);

    f32x4 o0[4], o1[4];
    f32x4 lv0 = (f32x4){0.f, 0.f, 0.f, 0.f};
    f32x4 lv1 = (f32x4){0.f, 0.f, 0.f, 0.f};
#pragma unroll
    for (int hf = 0; hf < 4; ++hf) {
        o0[hf] = (f32x4){0.f, 0.f, 0.f, 0.f};
        o1[hf] = (f32x4){0.f, 0.f, 0.f, 0.f};
    }

    // staging: wave stages bytes [wave*2K, wave*2K+2K) of each 8KB tile
    const char* kbase = (const char*)Kf + ((long)(b * 256) << 11);
    const char* vbase = (const char*)Vf + ((long)(b * 64) << 13);
#define STAGE(kc_, buf_)                                                             \
    do {                                                                             \
        const char* ks_ = kbase + ((long)(kc_) << 13) + wave * 2048 + lane * 16;     \
        const char* vs_ = vbase + ((long)(kc_) << 13) + wave * 2048 + lane * 16;     \
        unsigned short* dk_ = &KV[buf_][wave * 1024];                                \
        unsigned short* dv_ = &KV[buf_][4096 + wave * 1024];                         \
        gload_lds16(ks_, dk_);                                                       \
        gload_lds16(ks_ + 1024, dk_ + 512);                                          \
        gload_lds16(vs_, dv_);                                                       \
        gload_lds16(vs_ + 1024, dv_ + 512);                                          \
    } while (0)

    STAGE(t0k, 0);
    if (ntt > 1) STAGE(t0k + 1, 1);

    unsigned short* pw0 = &Ps[wave * 2 + 0][0];
    unsigned short* pw1 = &Ps[wave * 2 + 1][0];

    for (int t = 0; t < ntt; ++t) {
        const int kc = t0k + t;
        const int buf = t & 1;
        if (t + 1 < ntt)
            asm volatile("s_waitcnt vmcnt(4)" ::: "memory");
        else
            asm volatile("s_waitcnt vmcnt(0)" ::: "memory");
        __builtin_amdgcn_sched_barrier(0);
        __builtin_amdgcn_s_barrier();  // buf staged for all waves

        const unsigned short* Kb = &KV[buf][0];
        const unsigned short* Vb = &KV[buf][4096];
        const int sbt = kc * 64;
        const bool do0 = (kc <= dt0);  // sub0 active (tile dt1 is sub1-only)

        // K fragments once, used by both subtiles
        bf16x8 kf[8];
#pragma unroll
        for (int ct = 0; ct < 4; ++ct) {
            kf[ct * 2 + 0] = *(const bf16x8*)&Kb[ct * 1024 + lane * 8];
            kf[ct * 2 + 1] = *(const bf16x8*)&Kb[ct * 1024 + 512 + lane * 8];
        }

        if (do0) {
            f32x4 st[4];
            __builtin_amdgcn_s_setprio(1);
#pragma unroll
            for (int ct = 0; ct < 4; ++ct) {
                f32x4 zz = (f32x4){0.f, 0.f, 0.f, 0.f};
                zz = mfma16(kf[ct * 2 + 0], qf00, zz);
                zz = mfma16(kf[ct * 2 + 1], qf01, zz);
                st[ct] = zz;
            }
            __builtin_amdgcn_s_setprio(0);
            if (kc == dt0) {
#pragma unroll
                for (int ct = 0; ct < 4; ++ct) {
                    const int sb = sbt + ct * 16 + quad * 4;
#pragma unroll
                    for (int r = 0; r < 4; ++r)
                        if (sb + r > qg0) st[ct][r] = -3.0e38f;
                }
            }
#pragma unroll
            for (int ct = 0; ct < 4; ++ct) {
#pragma unroll
                for (int r = 0; r < 4; ++r)
                    st[ct][r] = __builtin_amdgcn_exp2f(st[ct][r]);
                lv0 += st[ct];
            }
#pragma unroll
            for (int ct = 0; ct < 4; ++ct) {
                unsigned int w0 = pkbf(st[ct][1], st[ct][0]);
                unsigned int w1 = pkbf(st[ct][3], st[ct][2]);
                *(uint2*)&pw0[lane15 * PSP + ct * 16 + quad * 4] = make_uint2(w0, w1);
            }
        }

        {
            f32x4 su[4];
            __builtin_amdgcn_s_setprio(1);
#pragma unroll
            for (int ct = 0; ct < 4; ++ct) {
                f32x4 zz = (f32x4){0.f, 0.f, 0.f, 0.f};
                zz = mfma16(kf[ct * 2 + 0], qf10, zz);
                zz = mfma16(kf[ct * 2 + 1], qf11, zz);
                su[ct] = zz;
            }
            __builtin_amdgcn_s_setprio(0);
            if (kc == dt1) {
                const int qg1 = qg0 + 64;
#pragma unroll
                for (int ct = 0; ct < 4; ++ct) {
                    const int sb = sbt + ct * 16 + quad * 4;
#pragma unroll
                    for (int r = 0; r < 4; ++r)
                        if (sb + r > qg1) su[ct][r] = -3.0e38f;
                }
            }
#pragma unroll
            for (int ct = 0; ct < 4; ++ct) {
#pragma unroll
                for (int r = 0; r < 4; ++r)
                    su[ct][r] = __builtin_amdgcn_exp2f(su[ct][r]);
                lv1 += su[ct];
            }
#pragma unroll
            for (int ct = 0; ct < 4; ++ct) {
                unsigned int w0 = pkbf(su[ct][1], su[ct][0]);
                unsigned int w1 = pkbf(su[ct][3], su[ct][2]);
                *(uint2*)&pw1[lane15 * PSP + ct * 16 + quad * 4] = make_uint2(w0, w1);
            }
        }

        // V fragments + PV for both subtiles
        bf16x8 vf[8];
#pragma unroll
        for (int f = 0; f < 8; ++f) vf[f] = *(const bf16x8*)&Vb[f * 512 + lane * 8];

        bf16x8 pa10 = *(const bf16x8*)&pw1[lane15 * PSP + quad * 8];
        bf16x8 pa11 = *(const bf16x8*)&pw1[lane15 * PSP + 32 + quad * 8];
        if (do0) {
            bf16x8 pa00 = *(const bf16x8*)&pw0[lane15 * PSP + quad * 8];
            bf16x8 pa01 = *(const bf16x8*)&pw0[lane15 * PSP + 32 + quad * 8];
            __builtin_amdgcn_s_setprio(1);
#pragma unroll
            for (int hf = 0; hf < 4; ++hf) {
                o0[hf] = mfma16(pa00, vf[hf * 2 + 0], o0[hf]);
                o0[hf] = mfma16(pa01, vf[hf * 2 + 1], o0[hf]);
            }
            __builtin_amdgcn_s_setprio(0);
        }
        __builtin_amdgcn_s_setprio(1);
#pragma unroll
        for (int hf = 0; hf < 4; ++hf) {
            o1[hf] = mfma16(pa10, vf[hf * 2 + 0], o1[hf]);
            o1[hf] = mfma16(pa11, vf[hf * 2 + 1], o1[hf]);
        }
        __builtin_amdgcn_s_setprio(0);

        __builtin_amdgcn_s_barrier();  // buf consumed by all waves
        if (t + 2 < ntt) STAGE(t0k + t + 2, buf);
    }
#undef STAGE

    // l folds: each lane ends with full row-sum for q = lane15 (per sub)
    float l0 = (lv0[0] + lv0[1]) + (lv0[2] + lv0[3]);
    l0 += __shfl_xor(l0, 16);
    l0 += __shfl_xor(l0, 32);
    float l1 = (lv1[0] + lv1[1]) + (lv1[2] + lv1[3]);
    l1 += __shfl_xor(l1, 16);
    l1 += __shfl_xor(l1, 32);

    if (qmt < 4) {
        // single-chunk macro-tile: normalize and write out directly
        float linv0[4], linv1[4];
#pragma unroll
        for (int r = 0; r < 4; ++r) {
            linv0[r] = 1.0f / __shfl(l0, quad * 4 + r);
            linv1[r] = 1.0f / __shfl(l1, quad * 4 + r);
        }
        float* o = out + ((long)b * T_ + qmt * 128 + wave * 16) * H_;
#pragma unroll
        for (int hf = 0; hf < 4; ++hf)
#pragma unroll
            for (int r = 0; r < 4; ++r)
                o[(quad * 4 + r) * H_ + hf * 16 + lane15] = o0[hf][r] * linv0[r];
        float* o2 = o + 64 * H_;
#pragma unroll
        for (int hf = 0; hf < 4; ++hf)
#pragma unroll
            for (int r = 0; r < 4; ++r)
                o2[(quad * 4 + r) * H_ + hf * 16 + lane15] = o1[hf][r] * linv1[r];
    } else {
        const long pb0 = ((long)(b * 64 + dt0) * 8 + chunk) * 64;
        if (quad == 0) lp[pb0 + wave * 16 + lane15] = l0;
        unsigned short* op0 = Opb + (pb0 + wave * 16) * 64;
#pragma unroll
        for (int hf = 0; hf < 4; ++hf)
#pragma unroll
            for (int r = 0; r < 4; ++r)
                op0[(quad * 4 + r) * 64 + hf * 16 + lane15] = f2bf(o0[hf][r]);
        const long pb1 = ((long)(b * 64 + dt1) * 8 + chunk) * 64;
        if (quad == 0) lp[pb1 + wave * 16 + lane15] = l1;
        unsigned short* op1 = Opb + (pb1 + wave * 16) * 64;
#pragma unroll
        for (int hf = 0; hf < 4; ++hf)
#pragma unroll
            for (int r = 0; r < 4; ++r)
                op1[(quad * 4 + r) * 64 + hf * 16 + lane15] = f2bf(o1[hf][r]);

        // --- last-arriver merge for this (b, qmt) macro-tile ---
        __threadfence();        // release: partials visible device-wide
        __syncthreads();        // all waves' stores issued+fenced
        if (tid == 0) {
            int old = atomicAdd(&cnt[b * 32 + qmt], 1);
            is_last = (old == g) ? 1 : 0;   // g+1 chunk blocks total
        }
        __syncthreads();
        if (is_last) {
            __threadfence();    // acquire: see all other blocks' partials
            const int row128 = tid >> 1;          // 0..127
            const int dt = dt0 + (row128 >> 6);   // dt0 rows then dt1 rows
            const int row = row128 & 63;
            const int seg = (tid & 1) << 5;       // h offset: 0 or 32
            const long mbase = (long)(b * 64 + dt) * 8;
            float l = 0.f;
            f32x4 a[8];
#pragma unroll
            for (int j = 0; j < 8; ++j) a[j] = (f32x4){0.f, 0.f, 0.f, 0.f};
            for (int c = 0; c <= g; ++c) {
                l += lp[(mbase + c) * 64 + row];
                const unsigned short* op = Opb + ((mbase + c) * 64 + row) * 64 + seg;
#pragma unroll
                for (int j = 0; j < 4; ++j) {
                    uint4 d = *(const uint4*)(op + j * 8);
                    a[j * 2 + 0][0] += bf2f_lo(d.x); a[j * 2 + 0][1] += bf2f_hi(d.x);
                    a[j * 2 + 0][2] += bf2f_lo(d.y); a[j * 2 + 0][3] += bf2f_hi(d.y);
                    a[j * 2 + 1][0] += bf2f_lo(d.z); a[j * 2 + 1][1] += bf2f_hi(d.z);
                    a[j * 2 + 1][2] += bf2f_lo(d.w); a[j * 2 + 1][3] += bf2f_hi(d.w);
                }
            }
            const float inv = 1.0f / l;
            float* o = out + ((long)b * T_ + dt * 64 + row) * H_ + seg;
#pragma unroll
            for (int j = 0; j < 8; ++j) *(f32x4*)(o + j * 4) = a[j] * inv;
        }
    }
}

// ---------------------------------------------------------------------------
extern "C" void kernel_launch(void* const* d_in, const int* in_sizes, int n_in,
                              void* d_out, int out_size, void* d_ws, size_t ws_size,
                              hipStream_t stream) {
    const float* x  = (const float*)d_in[0];
    const float* Wk = (const float*)d_in[1];
    const float* Wq = (const float*)d_in[2];
    const float* Wv = (const float*)d_in[3];
    float* out = (float*)d_out;

    char* ws = (char*)d_ws;
    unsigned short* Kf  = (unsigned short*)(ws);                // 2 MB
    unsigned short* Qf  = (unsigned short*)(ws + (2u << 20));   // 2 MB
    unsigned short* Vf  = (unsigned short*)(ws + (4u << 20));   // 2 MB
    unsigned short* Wtp = (unsigned short*)(ws + (6u << 20));   // 192 KB
    unsigned short* Opb = (unsigned short*)(ws + (8u << 20));   // 16.8 MB
    float* lp = (float*)(ws + (26u << 20));                     // 512 KB
    int* cnt = (int*)(ws + (27u << 20));                        // 512 B

    wt_kernel<<<384, 256, 0, stream>>>(Wk, Wq, Wv, Wtp, cnt);
    proj_kernel<<<BT / 32, 256, 0, stream>>>(x, Wtp, Kf, Qf, Vf);
    attn_kernel<<<dim3(144, B_), 256, 0, stream>>>(Qf, Kf, Vf, Opb, lp, cnt, out);
}

// Round 7
// 109.080 us; speedup vs baseline: 1.9752x; 1.9752x over previous
//
#include <hip/hip_runtime.h>

// B=4, T=4096, C=512, H=64 causal attention head, scale=C^-0.5, fp32 I/O.
// R18 = R16 revert (R17's fused last-arriver merge stalled on per-block
// device-scope fences: L2 wb/inv x1120 -> attn 137us) + XCD-pinned batch
// swizzle: 1D grid 576, xcd=L&7 -> batch=xcd>>1, so each batch's K/V/Q
// (~1.5MB) stays resident in its 2 XCDs' L2 (attn FETCH 22MB -> ~8MB).

typedef __attribute__((ext_vector_type(8))) __bf16 bf16x8;
typedef __attribute__((ext_vector_type(8))) unsigned short u16x8;
typedef __attribute__((ext_vector_type(4))) float f32x4;

#define B_ 4
#define T_ 4096
#define C_ 512
#define H_ 64
#define BT (B_ * T_)

#define QSCALE (0.04419417382415922f * 1.4426950408889634f)  // C^-0.5 * log2(e)

__device__ __forceinline__ unsigned short f2bf(float f) {
    unsigned int u = __builtin_bit_cast(unsigned int, f);
    u += 0x7fffu + ((u >> 16) & 1u);
    return (unsigned short)(u >> 16);
}

__device__ __forceinline__ unsigned int pkbf(float hi, float lo) {
    return __builtin_amdgcn_perm(__builtin_bit_cast(unsigned int, hi),
                                 __builtin_bit_cast(unsigned int, lo), 0x07060302u);
}

__device__ __forceinline__ float bf2f_lo(unsigned int u) {
    return __builtin_bit_cast(float, u << 16);
}
__device__ __forceinline__ float bf2f_hi(unsigned int u) {
    return __builtin_bit_cast(float, u & 0xffff0000u);
}

__device__ __forceinline__ f32x4 mfma16(bf16x8 a, bf16x8 b, f32x4 c) {
    return __builtin_amdgcn_mfma_f32_16x16x32_bf16(a, b, c, 0, 0, 0);
}

// async global->LDS, 16B per lane; lds dest must be the wave-uniform base.
__device__ __forceinline__ void gload_lds16(const void* g, void* lds_uniform) {
    __builtin_amdgcn_global_load_lds(
        (const __attribute__((address_space(1))) unsigned int*)g,
        (__attribute__((address_space(3))) unsigned int*)lds_uniform, 16, 0, 0);
}

// ---------------------------------------------------------------------------
// Kernel 0: Wt packed in MFMA B-fragment order.
// ---------------------------------------------------------------------------
__global__ __launch_bounds__(256) void wt_kernel(const float* __restrict__ Wk,
                                                 const float* __restrict__ Wq,
                                                 const float* __restrict__ Wv,
                                                 unsigned short* __restrict__ Wtp) {
    int gid = blockIdx.x * 256 + threadIdx.x;  // 3*64*512
    int fidx = gid >> 9;
    int li = gid & 511;
    int lane = li >> 3, j = li & 7;
    int m3 = fidx / 64;
    int rem = fidx & 63;
    int nt = rem >> 4, kc = rem & 15;
    int h = nt * 16 + (lane & 15);
    int c = kc * 32 + (lane >> 4) * 8 + j;
    const float* W = (m3 == 0) ? Wk : ((m3 == 1) ? Wq : Wv);
    Wtp[gid] = f2bf(W[c * H_ + h]);
}

// ---------------------------------------------------------------------------
// Kernel 1: projections. 32 rows/block, 256 thr = 2 strips x 2 kc-halves,
// register prefetch of x TWO kc ahead (HBM latency) + W one kc ahead (L2).
// ---------------------------------------------------------------------------
__global__ __launch_bounds__(256, 3) void proj_kernel(const float* __restrict__ x,
                                                      const unsigned short* __restrict__ Wtp,
                                                      unsigned short* __restrict__ Kf,
                                                      unsigned short* __restrict__ Qf,
                                                      unsigned short* __restrict__ Vf) {
    __shared__ __align__(16) char smem[2 * 64 * 52 * 4];   // 26624 B
    float* Mg = (float*)smem;                               // [2][64][52] f32
    unsigned short* Ks_l = (unsigned short*)smem;           // [32][68]
    unsigned short* Qs_l = Ks_l + 32 * 68;
    unsigned short* Vt_l = Qs_l + 32 * 68;                  // [64 h][34]

    const int tid = threadIdx.x;
    const int t0 = blockIdx.x * 32;
    const int wave = tid >> 6;
    const int ws = wave & 1;       // strip
    const int wh = wave >> 1;      // kc half
    const int lane = tid & 63;
    const int lane15 = lane & 15;
    const int quad = lane >> 4;

    f32x4 acc[12];
#pragma unroll
    for (int i = 0; i < 12; ++i) acc[i] = (f32x4){0.f, 0.f, 0.f, 0.f};

    const float* xrow = x + (long)(t0 + ws * 16 + lane15) * C_;
    const unsigned short* wbase = Wtp + lane * 8;

    bf16x8 wf[12];
    float4 xa0[2], xa1[2];
    {
        const int kc0 = wh * 8;
        xa0[0] = *(const float4*)(xrow + kc0 * 32 + quad * 8);
        xa1[0] = *(const float4*)(xrow + kc0 * 32 + quad * 8 + 4);
        xa0[1] = *(const float4*)(xrow + (kc0 + 1) * 32 + quad * 8);
        xa1[1] = *(const float4*)(xrow + (kc0 + 1) * 32 + quad * 8 + 4);
#pragma unroll
        for (int i = 0; i < 12; ++i)
            wf[i] = *(const bf16x8*)(wbase + ((i * 16 + kc0) << 9));
    }

#pragma unroll
    for (int kk = 0; kk < 8; ++kk) {
        const int kc = wh * 8 + kk;
        const int cur = kk & 1;
        u16x8 t;
        t[0] = f2bf(xa0[cur].x); t[1] = f2bf(xa0[cur].y);
        t[2] = f2bf(xa0[cur].z); t[3] = f2bf(xa0[cur].w);
        t[4] = f2bf(xa1[cur].x); t[5] = f2bf(xa1[cur].y);
        t[6] = f2bf(xa1[cur].z); t[7] = f2bf(xa1[cur].w);
        bf16x8 a = __builtin_bit_cast(bf16x8, t);
        if (kk < 6) {
            xa0[cur] = *(const float4*)(xrow + (kc + 2) * 32 + quad * 8);
            xa1[cur] = *(const float4*)(xrow + (kc + 2) * 32 + quad * 8 + 4);
        }
        __builtin_amdgcn_s_setprio(1);
#pragma unroll
        for (int i = 0; i < 12; ++i) {
            acc[i] = mfma16(a, wf[i], acc[i]);
            if (kk < 7)
                wf[i] = *(const bf16x8*)(wbase + ((i * 16 + kc + 1) << 9));
        }
        __builtin_amdgcn_s_setprio(0);
    }

    // kc merge through LDS
    if (wh == 1) {
        float* mg = Mg + (ws * 64 + lane) * 52;
#pragma unroll
        for (int i = 0; i < 12; ++i) *(f32x4*)(mg + i * 4) = acc[i];
    }
    __syncthreads();
    if (wh == 0) {
        const float* mg = Mg + (ws * 64 + lane) * 52;
#pragma unroll
        for (int i = 0; i < 12; ++i) acc[i] += *(const f32x4*)(mg + i * 4);
    }
    __syncthreads();  // Mg dead

    if (wh == 0) {
#pragma unroll
        for (int nt = 0; nt < 4; ++nt) {
            int col = nt * 16 + lane15;
#pragma unroll
            for (int r = 0; r < 4; ++r) {
                int row_l = ws * 16 + quad * 4 + r;
                Ks_l[row_l * 68 + col] = f2bf(acc[0 * 4 + nt][r]);
                Qs_l[row_l * 68 + col] = f2bf(acc[1 * 4 + nt][r] * QSCALE);
                Vt_l[col * 34 + row_l] = f2bf(acc[2 * 4 + nt][r]);
            }
        }
    }
    __syncthreads();

    const int b = t0 >> 12;
    const int tloc = t0 & 4095;
    const int st = wave >> 1, kk = wave & 1;
    const long gs = (long)(b * 256 + (tloc >> 4) + st);
    bf16x8 kv = *(const bf16x8*)&Ks_l[(st * 16 + lane15) * 68 + kk * 32 + quad * 8];
    *(bf16x8*)&Kf[(gs * 2 + kk) * 512 + lane * 8] = kv;
    bf16x8 qv = *(const bf16x8*)&Qs_l[(st * 16 + lane15) * 68 + kk * 32 + quad * 8];
    *(bf16x8*)&Qf[(gs * 2 + kk) * 512 + lane * 8] = qv;
    const int hf = wave;
    const int vkk = (tloc >> 5) & 1;
    bf16x8 vv = *(const bf16x8*)&Vt_l[(hf * 16 + lane15) * 34 + quad * 8];
    const long sb = (long)(b * 64 + (tloc >> 6));
    *(bf16x8*)&Vf[(sb * 8 + hf * 2 + vkk) * 512 + lane * 8] = vv;
}

// ---------------------------------------------------------------------------
// Kernel 2: attention. 1D grid 576; xcd=L&7 pins batch b=xcd>>1 to 2 XCDs.
// Block = (b, 128-row q macro-tile, chunk of <=8 K tiles). 4 waves x 2
// q-subtiles. K/V LDS-staged (global_load_lds, dbuf, counted vmcnt).
// ---------------------------------------------------------------------------
#define PSP 72

__global__ __launch_bounds__(256, 3) void attn_kernel(const unsigned short* __restrict__ Qf,
                                                      const unsigned short* __restrict__ Kf,
                                                      const unsigned short* __restrict__ Vf,
                                                      unsigned short* __restrict__ Opb,
                                                      float* __restrict__ lp,
                                                      float* __restrict__ out) {
    __shared__ __align__(16) unsigned short KV[2][8192];       // 32 KB: [buf][K 8KB | V 8KB]
    __shared__ __align__(16) unsigned short Ps[8][16 * PSP];   // 18432 B: [wave*2+sub]

    const int tid = threadIdx.x;
    const int wave = tid >> 6;
    const int lane = tid & 63;
    const int lane15 = lane & 15;
    const int quad = lane >> 4;

    // XCD-pinned decode: L%8 -> xcd; batch = xcd>>1; j enumerates the 144
    // work items of that batch (bijective: 72 L-values x 2 xcds per batch).
    const int L = blockIdx.x;
    const int xcd = L & 7;
    const int b = xcd >> 1;
    const int j = ((L >> 3) << 1) | (xcd & 1);

    // longest chunks first within batch. Group g = qmt>>2 has 4 qmt x (g+1)
    // chunks, base 2g(g+1).
    const int z = 143 - j;
    int g = (int)((__builtin_sqrtf(2.0f * (float)z + 1.0f) - 1.0f) * 0.5f);
    while (2 * (g + 1) * (g + 2) <= z) ++g;
    while (2 * g * (g + 1) > z) --g;
    const int idx = z - 2 * g * (g + 1);
    const int qmt = g * 4 + idx / (g + 1);
    const int chunk = idx % (g + 1);
    const int ntt = min(8, 2 * qmt + 2 - chunk * 8);
    const int t0k = chunk * 8;
    const int dt0 = 2 * qmt, dt1 = 2 * qmt + 1;
    const int qg0 = qmt * 128 + wave * 16 + lane15;

    // Q fragments for both sub-tiles
    const long gq = (long)(b * 256 + qmt * 8 + wave);
    const unsigned short* qb = Qf + gq * 1024 + lane * 8;
    const bf16x8 qf00 = *(const bf16x8*)qb;
    const bf16x8 qf01 = *(const bf16x8*)(qb + 512);
    const bf16x8 qf10 = *(const bf16x8*)(qb + 4096);
    const bf16x8 qf11 = *(const bf16x8*)(qb + 4096 + 512);

    f32x4 o0[4], o1[4];
    f32x4 lv0 = (f32x4){0.f, 0.f, 0.f, 0.f};
    f32x4 lv1 = (f32x4){0.f, 0.f, 0.f, 0.f};
#pragma unroll
    for (int hf = 0; hf < 4; ++hf) {
        o0[hf] = (f32x4){0.f, 0.f, 0.f, 0.f};
        o1[hf] = (f32x4){0.f, 0.f, 0.f, 0.f};
    }

    // staging: wave stages bytes [wave*2K, wave*2K+2K) of each 8KB tile
    const char* kbase = (const char*)Kf + ((long)(b * 256) << 11);
    const char* vbase = (const char*)Vf + ((long)(b * 64) << 13);
#define STAGE(kc_, buf_)                                                             \
    do {                                                                             \
        const char* ks_ = kbase + ((long)(kc_) << 13) + wave * 2048 + lane * 16;     \
        const char* vs_ = vbase + ((long)(kc_) << 13) + wave * 2048 + lane * 16;     \
        unsigned short* dk_ = &KV[buf_][wave * 1024];                                \
        unsigned short* dv_ = &KV[buf_][4096 + wave * 1024];                         \
        gload_lds16(ks_, dk_);                                                       \
        gload_lds16(ks_ + 1024, dk_ + 512);                                          \
        gload_lds16(vs_, dv_);                                                       \
        gload_lds16(vs_ + 1024, dv_ + 512);                                          \
    } while (0)

    STAGE(t0k, 0);
    if (ntt > 1) STAGE(t0k + 1, 1);

    unsigned short* pw0 = &Ps[wave * 2 + 0][0];
    unsigned short* pw1 = &Ps[wave * 2 + 1][0];

    for (int t = 0; t < ntt; ++t) {
        const int kc = t0k + t;
        const int buf = t & 1;
        if (t + 1 < ntt)
            asm volatile("s_waitcnt vmcnt(4)" ::: "memory");
        else
            asm volatile("s_waitcnt vmcnt(0)" ::: "memory");
        __builtin_amdgcn_sched_barrier(0);
        __builtin_amdgcn_s_barrier();  // buf staged for all waves

        const unsigned short* Kb = &KV[buf][0];
        const unsigned short* Vb = &KV[buf][4096];
        const int sbt = kc * 64;
        const bool do0 = (kc <= dt0);  // sub0 active (tile dt1 is sub1-only)

        // K fragments once, used by both subtiles
        bf16x8 kf[8];
#pragma unroll
        for (int ct = 0; ct < 4; ++ct) {
            kf[ct * 2 + 0] = *(const bf16x8*)&Kb[ct * 1024 + lane * 8];
            kf[ct * 2 + 1] = *(const bf16x8*)&Kb[ct * 1024 + 512 + lane * 8];
        }

        if (do0) {
            f32x4 st[4];
            __builtin_amdgcn_s_setprio(1);
#pragma unroll
            for (int ct = 0; ct < 4; ++ct) {
                f32x4 zz = (f32x4){0.f, 0.f, 0.f, 0.f};
                zz = mfma16(kf[ct * 2 + 0], qf00, zz);
                zz = mfma16(kf[ct * 2 + 1], qf01, zz);
                st[ct] = zz;
            }
            __builtin_amdgcn_s_setprio(0);
            if (kc == dt0) {
#pragma unroll
                for (int ct = 0; ct < 4; ++ct) {
                    const int sb = sbt + ct * 16 + quad * 4;
#pragma unroll
                    for (int r = 0; r < 4; ++r)
                        if (sb + r > qg0) st[ct][r] = -3.0e38f;
                }
            }
#pragma unroll
            for (int ct = 0; ct < 4; ++ct) {
#pragma unroll
                for (int r = 0; r < 4; ++r)
                    st[ct][r] = __builtin_amdgcn_exp2f(st[ct][r]);
                lv0 += st[ct];
            }
#pragma unroll
            for (int ct = 0; ct < 4; ++ct) {
                unsigned int w0 = pkbf(st[ct][1], st[ct][0]);
                unsigned int w1 = pkbf(st[ct][3], st[ct][2]);
                *(uint2*)&pw0[lane15 * PSP + ct * 16 + quad * 4] = make_uint2(w0, w1);
            }
        }

        {
            f32x4 su[4];
            __builtin_amdgcn_s_setprio(1);
#pragma unroll
            for (int ct = 0; ct < 4; ++ct) {
                f32x4 zz = (f32x4){0.f, 0.f, 0.f, 0.f};
                zz = mfma16(kf[ct * 2 + 0], qf10, zz);
                zz = mfma16(kf[ct * 2 + 1], qf11, zz);
                su[ct] = zz;
            }
            __builtin_amdgcn_s_setprio(0);
            if (kc == dt1) {
                const int qg1 = qg0 + 64;
#pragma unroll
                for (int ct = 0; ct < 4; ++ct) {
                    const int sb = sbt + ct * 16 + quad * 4;
#pragma unroll
                    for (int r = 0; r < 4; ++r)
                        if (sb + r > qg1) su[ct][r] = -3.0e38f;
                }
            }
#pragma unroll
            for (int ct = 0; ct < 4; ++ct) {
#pragma unroll
                for (int r = 0; r < 4; ++r)
                    su[ct][r] = __builtin_amdgcn_exp2f(su[ct][r]);
                lv1 += su[ct];
            }
#pragma unroll
            for (int ct = 0; ct < 4; ++ct) {
                unsigned int w0 = pkbf(su[ct][1], su[ct][0]);
                unsigned int w1 = pkbf(su[ct][3], su[ct][2]);
                *(uint2*)&pw1[lane15 * PSP + ct * 16 + quad * 4] = make_uint2(w0, w1);
            }
        }

        // V fragments + PV for both subtiles
        bf16x8 vf[8];
#pragma unroll
        for (int f = 0; f < 8; ++f) vf[f] = *(const bf16x8*)&Vb[f * 512 + lane * 8];

        bf16x8 pa10 = *(const bf16x8*)&pw1[lane15 * PSP + quad * 8];
        bf16x8 pa11 = *(const bf16x8*)&pw1[lane15 * PSP + 32 + quad * 8];
        if (do0) {
            bf16x8 pa00 = *(const bf16x8*)&pw0[lane15 * PSP + quad * 8];
            bf16x8 pa01 = *(const bf16x8*)&pw0[lane15 * PSP + 32 + quad * 8];
            __builtin_amdgcn_s_setprio(1);
#pragma unroll
            for (int hf = 0; hf < 4; ++hf) {
                o0[hf] = mfma16(pa00, vf[hf * 2 + 0], o0[hf]);
                o0[hf] = mfma16(pa01, vf[hf * 2 + 1], o0[hf]);
            }
            __builtin_amdgcn_s_setprio(0);
        }
        __builtin_amdgcn_s_setprio(1);
#pragma unroll
        for (int hf = 0; hf < 4; ++hf) {
            o1[hf] = mfma16(pa10, vf[hf * 2 + 0], o1[hf]);
            o1[hf] = mfma16(pa11, vf[hf * 2 + 1], o1[hf]);
        }
        __builtin_amdgcn_s_setprio(0);

        __builtin_amdgcn_s_barrier();  // buf consumed by all waves
        if (t + 2 < ntt) STAGE(t0k + t + 2, buf);
    }
#undef STAGE

    // l folds: each lane ends with full row-sum for q = lane15 (per sub)
    float l0 = (lv0[0] + lv0[1]) + (lv0[2] + lv0[3]);
    l0 += __shfl_xor(l0, 16);
    l0 += __shfl_xor(l0, 32);
    float l1 = (lv1[0] + lv1[1]) + (lv1[2] + lv1[3]);
    l1 += __shfl_xor(l1, 16);
    l1 += __shfl_xor(l1, 32);

    if (qmt < 4) {
        // single-chunk macro-tile: normalize and write out directly
        float linv0[4], linv1[4];
#pragma unroll
        for (int r = 0; r < 4; ++r) {
            linv0[r] = 1.0f / __shfl(l0, quad * 4 + r);
            linv1[r] = 1.0f / __shfl(l1, quad * 4 + r);
        }
        float* o = out + ((long)b * T_ + qmt * 128 + wave * 16) * H_;
#pragma unroll
        for (int hf = 0; hf < 4; ++hf)
#pragma unroll
            for (int r = 0; r < 4; ++r)
                o[(quad * 4 + r) * H_ + hf * 16 + lane15] = o0[hf][r] * linv0[r];
        float* o2 = o + 64 * H_;
#pragma unroll
        for (int hf = 0; hf < 4; ++hf)
#pragma unroll
            for (int r = 0; r < 4; ++r)
                o2[(quad * 4 + r) * H_ + hf * 16 + lane15] = o1[hf][r] * linv1[r];
    } else {
        const long pb0 = ((long)(b * 64 + dt0) * 8 + chunk) * 64;
        if (quad == 0) lp[pb0 + wave * 16 + lane15] = l0;
        unsigned short* op0 = Opb + (pb0 + wave * 16) * 64;
#pragma unroll
        for (int hf = 0; hf < 4; ++hf)
#pragma unroll
            for (int r = 0; r < 4; ++r)
                op0[(quad * 4 + r) * 64 + hf * 16 + lane15] = f2bf(o0[hf][r]);
        const long pb1 = ((long)(b * 64 + dt1) * 8 + chunk) * 64;
        if (quad == 0) lp[pb1 + wave * 16 + lane15] = l1;
        unsigned short* op1 = Opb + (pb1 + wave * 16) * 64;
#pragma unroll
        for (int hf = 0; hf < 4; ++hf)
#pragma unroll
            for (int r = 0; r < 4; ++r)
                op1[(quad * 4 + r) * 64 + hf * 16 + lane15] = f2bf(o1[hf][r]);
    }
}

// ---------------------------------------------------------------------------
// Kernel 3: merge bf16 chunk partials for qt in [8, 64). Block = 32 rows of
// one (qt, b): grid (112, B). 8 h per thread, unroll-2 chunk loop.
// ---------------------------------------------------------------------------
__global__ __launch_bounds__(256) void merge_kernel(const unsigned short* __restrict__ Opb,
                                                    const float* __restrict__ lp,
                                                    float* __restrict__ out) {
    const int qt = 8 + (blockIdx.x >> 1);
    const int rh = (blockIdx.x & 1) << 5;   // row half: 0 or 32
    const int b = blockIdx.y;
    const int nc = 1 + (qt >> 3);   // 2..8
    const int tid = threadIdx.x;
    const int row = rh + (tid >> 3);
    const int seg = (tid & 7) << 3;  // 8 h per thread

    const long base = (long)(b * 64 + qt) * 8;
    float l = 0.f;
    f32x4 a0 = (f32x4){0.f, 0.f, 0.f, 0.f};
    f32x4 a1 = (f32x4){0.f, 0.f, 0.f, 0.f};

#pragma unroll 2
    for (int c = 0; c < nc; ++c) {
        l += lp[(base + c) * 64 + row];
        const unsigned short* op = Opb + ((base + c) * 64 + row) * 64 + seg;
        uint4 d = *(const uint4*)op;
        a0[0] += bf2f_lo(d.x); a0[1] += bf2f_hi(d.x);
        a0[2] += bf2f_lo(d.y); a0[3] += bf2f_hi(d.y);
        a1[0] += bf2f_lo(d.z); a1[1] += bf2f_hi(d.z);
        a1[2] += bf2f_lo(d.w); a1[3] += bf2f_hi(d.w);
    }
    const float inv = 1.0f / l;
    float* o = out + ((long)b * T_ + qt * 64 + row) * H_ + seg;
    *(f32x4*)o = a0 * inv;
    *(f32x4*)(o + 4) = a1 * inv;
}

// ---------------------------------------------------------------------------
extern "C" void kernel_launch(void* const* d_in, const int* in_sizes, int n_in,
                              void* d_out, int out_size, void* d_ws, size_t ws_size,
                              hipStream_t stream) {
    const float* x  = (const float*)d_in[0];
    const float* Wk = (const float*)d_in[1];
    const float* Wq = (const float*)d_in[2];
    const float* Wv = (const float*)d_in[3];
    float* out = (float*)d_out;

    char* ws = (char*)d_ws;
    unsigned short* Kf  = (unsigned short*)(ws);                // 2 MB
    unsigned short* Qf  = (unsigned short*)(ws + (2u << 20));   // 2 MB
    unsigned short* Vf  = (unsigned short*)(ws + (4u << 20));   // 2 MB
    unsigned short* Wtp = (unsigned short*)(ws + (6u << 20));   // 192 KB
    unsigned short* Opb = (unsigned short*)(ws + (8u << 20));   // 16.8 MB
    float* lp = (float*)(ws + (26u << 20));                     // 512 KB

    wt_kernel<<<384, 256, 0, stream>>>(Wk, Wq, Wv, Wtp);
    proj_kernel<<<BT / 32, 256, 0, stream>>>(x, Wtp, Kf, Qf, Vf);
    attn_kernel<<<576, 256, 0, stream>>>(Qf, Kf, Vf, Opb, lp, out);
    merge_kernel<<<dim3(112, B_), 256, 0, stream>>>(Opb, lp, out);
}